// Round 3
// baseline (346.661 us; speedup 1.0000x reference)
//
// PointNet++ FP: three_nn + three_interpolate + pointwise MLP(384->256->128)
// Round 11: LDS 48KB -> 32KB to hit the wave-slot ceiling. r10 counters:
// Occupancy 52.8% (3 blocks/CU, LDS-limited), VALU 66%, hard issue-work only
// ~36us of the 110us wall -> latency slack remains; occupancy is the lever.
// Change: skip features (points1, cols 256..383) no longer staged in LDS --
// layer-1 kk=8..11 builds A-fragments straight from global (r9-proven path).
// Xs shrinks to [64][256] bf16 = 32KB -> 4 blocks/CU (wave-slot limited),
// 32 waves/CU ~ 100% slots; grid 1024 = exactly 4 blocks/CU.
//  * scan (s_load ping-pong, wave=chunk, lane=point) unchanged from r10.
//  * all-lane redundant fold unchanged.
//  * Xs/Y1 XOR-swizzle (byte^=(row&7)<<4) unchanged; Y1 overlays Xs 1:1.
// 5 barriers: scan->fold->gather->L1->Y1->L2.
// MFMA 16x16x32 bf16 layouts (learn_hip m89/m120 verified):
//   A: [m=lane&15][k=(lane>>4)*8+j]   B: [k=(lane>>4)*8+j][n=lane&15]
//   D: [row=(lane>>4)*4+reg][col=lane&15]
#include <hip/hip_runtime.h>

typedef __bf16 bf16_t;
typedef bf16_t bf16x2_t __attribute__((ext_vector_type(2)));
typedef bf16_t bf16x4_t __attribute__((ext_vector_type(4)));
typedef bf16_t bf16x8_t __attribute__((ext_vector_type(8)));
typedef float floatx4_t __attribute__((ext_vector_type(4)));

constexpr int B_ = 8, N_ = 8192, M_ = 2048;
constexpr int C1 = 128, C2 = 256;
constexpr int K1 = 384, N1 = 256, N2 = 128;

// ws layout (bytes) -- unchanged
constexpr size_t WS_W1T   = 0;         // bf16  [256][384]  = 196608 B
constexpr size_t WS_W2T   = 196608;    // bf16  [128][256]  =  65536 B
constexpr size_t WS_XYZ2P = 262144;    // float4[8*2048]    = 262144 B

// ---------------------------------------------------------------- prep ----
__global__ __launch_bounds__(256) void prep_kernel(
    const float* __restrict__ W1, const float* __restrict__ W2,
    const float* __restrict__ xyz2,
    bf16_t* __restrict__ W1T, bf16_t* __restrict__ W2T,
    float4* __restrict__ xyz2p) {
  int bid = blockIdx.x, tid = threadIdx.x;
  if (bid < 384) {                       // W1 [384][256] -> W1T [256][384]
    int t = bid * 256 + tid;             // 98304 elems
    int n = t / K1, k = t - n * K1;
    W1T[t] = (bf16_t)W1[k * N1 + n];
  } else if (bid < 512) {                // W2 [256][128] -> W2T [128][256]
    int t = (bid - 384) * 256 + tid;     // 32768 elems
    int n = t / N1, k = t - n * N1;
    W2T[t] = (bf16_t)W2[k * N2 + n];
  } else {                               // xyz2 -> float4{x,y,z,|q|^2}
    int t = (bid - 512) * 256 + tid;     // 16384 elems
    const float* p = xyz2 + (size_t)t * 3;
    float x = p[0], y = p[1], z = p[2];
    xyz2p[t] = make_float4(x, y, z, x * x + y * y + z * z);
  }
}

// ---------------------------------------------- fused nn+interp+MLP -------
// 1024 blocks x 512 threads; block owns 64 points of batch b = bi&7 (XCD-local
// points2/xyz2p in that XCD's L2). Wave w = candidate chunk of 256.
__global__ __launch_bounds__(512, 8) void fp_fused_kernel(
    const float* __restrict__ xyz1, const float4* __restrict__ xyz2p,
    const float* __restrict__ points1, const float* __restrict__ points2,
    const bf16_t* __restrict__ W1T, const float* __restrict__ b1,
    const bf16_t* __restrict__ W2T, const float* __restrict__ b2,
    float* __restrict__ out) {
  // Xs [64][256] bf16 swizzled (32KB); sd/si [8][64] float4/int4 overlay the
  // first 16KB during the scan; Y1 [64][256] bf16 overlays after layer 1.
  __shared__ __align__(16) char smem[64 * 512];   // 32768 B

  int bi = blockIdx.x;
  int b = bi & 7;                  // batch -> XCD (round-robin)
  int base = (bi >> 3) * 64;       // tile within batch (0..127)
  int tid = threadIdx.x;
  int wave = __builtin_amdgcn_readfirstlane(tid >> 6);  // 0..7
  int lane = tid & 63;
  size_t bN = (size_t)b * N_ + base;

  float4* sdv = (float4*)smem;             // [8][64] biased top-3 dists
  int4*   siv = (int4*)(smem + 8192);      // [8][64] top-3 indices

  float w0, w1, w2;                // blend weights (lane = point)
  int   i0, i1, i2;                // top-3 indices (lane = point)

  // ===== Phase S: three_nn. wave=chunk of 256 cands, lane=point (uniform
  // candidate addresses -> s_load ping-pong; SGPR-fed VALU). ================
  {
    const float* p1 = xyz1 + (bN + lane) * 3;
    float x = p1[0], y = p1[1], z = p1[2];
    float sq1 = x * x + y * y + z * z;
    float m2x = -2.0f * x, m2y = -2.0f * y, m2z = -2.0f * z;

    const float4* p2 = xyz2p + b * M_ + (wave << 8);  // wave-uniform base
    int jb = wave << 8;

    float cd0[4], cd1[4], cd2[4];
    int   ci0[4], ci1[4], ci2[4];
#pragma unroll
    for (int t = 0; t < 4; ++t) {
      cd0[t] = 1e30f; cd1[t] = 1e30f; cd2[t] = 1e30f;
      ci0[t] = 0; ci1[t] = 0; ci2[t] = 0;
    }
    // top-3 insert on d_rel = d2 - sq1 (per-point constant shift, same argmin)
    auto proc = [&](const float4& qv, int jj) {
      int tc = jj & 3;                       // chain id (const after unroll)
      float d = fmaf(m2x, qv.x, fmaf(m2y, qv.y, fmaf(m2z, qv.z, qv.w)));
      bool l0 = d < cd0[tc], l1 = d < cd1[tc], l2 = d < cd2[tc];
      float n0v = fminf(cd0[tc], d);
      float n1v = __builtin_amdgcn_fmed3f(d, cd0[tc], cd1[tc]);
      float n2v = __builtin_amdgcn_fmed3f(d, cd1[tc], cd2[tc]);
      int t1 = l0 ? ci0[tc] : jj;            // carry into slot1
      int t2 = l1 ? ci1[tc] : jj;            // carry into slot2
      ci0[tc] = l0 ? jj : ci0[tc];
      ci1[tc] = l1 ? t1 : ci1[tc];
      ci2[tc] = l2 ? t2 : ci2[tc];
      cd0[tc] = n0v; cd1[tc] = n1v; cd2[tc] = n2v;
    };

    float4 bA[8], bB[8];
#pragma unroll
    for (int t = 0; t < 8; ++t) bA[t] = p2[t];
    for (int j = 0; j < 256; j += 16) {
#pragma unroll
      for (int t = 0; t < 8; ++t) bB[t] = p2[j + 8 + t];
#pragma unroll
      for (int t = 0; t < 8; ++t) proc(bA[t], jb + j + t);
      if (j + 16 < 256) {
#pragma unroll
        for (int t = 0; t < 8; ++t) bA[t] = p2[j + 16 + t];
      }
#pragma unroll
      for (int t = 0; t < 8; ++t) proc(bB[t], jb + j + 8 + t);
    }

    // merge the 4 chains -> sorted s0<=s1<=s2
    float s0 = cd0[0], s1 = cd1[0], s2 = cd2[0];
    int   a0 = ci0[0], a1 = ci1[0], a2 = ci2[0];
    auto ins = [&](float d, int j) {
      if (d < s2) {
        if (d < s1) {
          s2 = s1; a2 = a1;
          if (d < s0) { s1 = s0; a1 = a0; s0 = d; a0 = j; }
          else        { s1 = d;  a1 = j; }
        } else { s2 = d; a2 = j; }
      }
    };
#pragma unroll
    for (int t = 1; t < 4; ++t) {
      ins(cd0[t], ci0[t]); ins(cd1[t], ci1[t]); ins(cd2[t], ci2[t]);
    }
    sdv[wave * 64 + lane] = make_float4(s0 + sq1, s1 + sq1, s2 + sq1, 0.0f);
    siv[wave * 64 + lane] = make_int4(a0, a1, a2, 0);
  }
  __syncthreads();

  // ===== Fold: every lane folds its point's 8 chunk-partials (redundant
  // across waves -> no serialization, results live in regs of lane=point). ===
  {
    float4 d0 = sdv[lane];  int4 x0 = siv[lane];
    float t0 = d0.x, t1 = d0.y, t2 = d0.z;
    int   a0 = x0.x, a1 = x0.y, a2 = x0.z;
    auto ins = [&](float d, int j) {
      if (d < t2) {
        if (d < t1) {
          t2 = t1; a2 = a1;
          if (d < t0) { t1 = t0; a1 = a0; t0 = d; a0 = j; }
          else        { t1 = d;  a1 = j; }
        } else { t2 = d; a2 = j; }
      }
    };
#pragma unroll
    for (int c = 1; c < 8; ++c) {
      float4 dd = sdv[c * 64 + lane];  int4 xx = siv[c * 64 + lane];
      ins(dd.x, xx.x); ins(dd.y, xx.y); ins(dd.z, xx.z);
    }
    float e0 = fmaxf(t0, 1e-10f), e1 = fmaxf(t1, 1e-10f), e2 = fmaxf(t2, 1e-10f);
    float r0 = 1.0f / e0, r1 = 1.0f / e1, r2 = 1.0f / e2;
    float rs = 1.0f / (r0 + r1 + r2);
    w0 = r0 * rs; w1 = r1 * rs; w2 = r2 * rs;
    i0 = a0; i1 = a1; i2 = a2;
  }
  __syncthreads();   // sd/si region about to be overwritten by Xs

  // ===== Phase A: gather -> Xs[64][256] bf16 swizzled =====================
  // wave w fills rows w*8..w*8+7 (interp features only).
#pragma unroll 2
  for (int i = 0; i < 8; ++i) {
    int p = wave * 8 + i;
    int j0 = __shfl(i0, p), j1 = __shfl(i1, p), j2 = __shfl(i2, p);
    float u0 = __shfl(w0, p), u1 = __shfl(w1, p), u2 = __shfl(w2, p);
    const float* g0 = points2 + ((size_t)b * M_ + j0) * C2 + lane * 4;
    const float* g1 = points2 + ((size_t)b * M_ + j1) * C2 + lane * 4;
    const float* g2 = points2 + ((size_t)b * M_ + j2) * C2 + lane * 4;
    float4 a0 = *(const float4*)g0;
    float4 a1 = *(const float4*)g1;
    float4 a2 = *(const float4*)g2;
    bf16x4_t v;
    v[0] = (bf16_t)(u0 * a0.x + u1 * a1.x + u2 * a2.x);
    v[1] = (bf16_t)(u0 * a0.y + u1 * a1.y + u2 * a2.y);
    v[2] = (bf16_t)(u0 * a0.z + u1 * a1.z + u2 * a2.z);
    v[3] = (bf16_t)(u0 * a0.w + u1 * a1.w + u2 * a2.w);
    int off = (p << 9) + ((lane * 8) ^ (i << 4));     // (p&7)==i
    *(bf16x4_t*)(smem + off) = v;
  }
  __syncthreads();

  int q = lane >> 4, r = lane & 15;
  int rs8 = (r & 7) << 4;            // row-swizzle XOR (rows r,16+r,32+r,48+r)

  // ---- Layer 1: [64 x 384] x [384 x 256] -> Y1, wave owns 32 cols
  floatx4_t acc[4][2] = {};
  int cw = wave * 32;
  const bf16_t* wq0 = W1T + (size_t)(cw +      r) * K1;
  const bf16_t* wq1 = W1T + (size_t)(cw + 16 + r) * K1;
  // interp part: K = 0..255 from LDS
  for (int kk = 0; kk < 8; ++kk) {
    int k0 = kk * 32 + q * 8;
    int co = (k0 << 1) ^ rs8;
    bf16x8_t a0 = *(const bf16x8_t*)(smem + ((     r) << 9) + co);
    bf16x8_t a1 = *(const bf16x8_t*)(smem + ((16 + r) << 9) + co);
    bf16x8_t a2 = *(const bf16x8_t*)(smem + ((32 + r) << 9) + co);
    bf16x8_t a3 = *(const bf16x8_t*)(smem + ((48 + r) << 9) + co);
    bf16x8_t bb0 = *(const bf16x8_t*)(wq0 + k0);
    bf16x8_t bb1 = *(const bf16x8_t*)(wq1 + k0);
    acc[0][0] = __builtin_amdgcn_mfma_f32_16x16x32_bf16(a0, bb0, acc[0][0], 0, 0, 0);
    acc[1][0] = __builtin_amdgcn_mfma_f32_16x16x32_bf16(a1, bb0, acc[1][0], 0, 0, 0);
    acc[2][0] = __builtin_amdgcn_mfma_f32_16x16x32_bf16(a2, bb0, acc[2][0], 0, 0, 0);
    acc[3][0] = __builtin_amdgcn_mfma_f32_16x16x32_bf16(a3, bb0, acc[3][0], 0, 0, 0);
    acc[0][1] = __builtin_amdgcn_mfma_f32_16x16x32_bf16(a0, bb1, acc[0][1], 0, 0, 0);
    acc[1][1] = __builtin_amdgcn_mfma_f32_16x16x32_bf16(a1, bb1, acc[1][1], 0, 0, 0);
    acc[2][1] = __builtin_amdgcn_mfma_f32_16x16x32_bf16(a2, bb1, acc[2][1], 0, 0, 0);
    acc[3][1] = __builtin_amdgcn_mfma_f32_16x16x32_bf16(a3, bb1, acc[3][1], 0, 0, 0);
  }
  // skip part: K = 256..383, A-fragments straight from points1 (no LDS)
#pragma unroll
  for (int kk2 = 0; kk2 < 4; ++kk2) {
    int c0 = kk2 * 32 + q * 8;
    bf16x8_t af[4];
#pragma unroll
    for (int t = 0; t < 4; ++t) {
      const float* sp = points1 + (bN + t * 16 + r) * (size_t)C1 + c0;
      float4 f0 = *(const float4*)sp;
      float4 f1 = *(const float4*)(sp + 4);
      af[t][0] = (bf16_t)f0.x; af[t][1] = (bf16_t)f0.y;
      af[t][2] = (bf16_t)f0.z; af[t][3] = (bf16_t)f0.w;
      af[t][4] = (bf16_t)f1.x; af[t][5] = (bf16_t)f1.y;
      af[t][6] = (bf16_t)f1.z; af[t][7] = (bf16_t)f1.w;
    }
    int k0 = 256 + c0;
    bf16x8_t bb0 = *(const bf16x8_t*)(wq0 + k0);
    bf16x8_t bb1 = *(const bf16x8_t*)(wq1 + k0);
    acc[0][0] = __builtin_amdgcn_mfma_f32_16x16x32_bf16(af[0], bb0, acc[0][0], 0, 0, 0);
    acc[1][0] = __builtin_amdgcn_mfma_f32_16x16x32_bf16(af[1], bb0, acc[1][0], 0, 0, 0);
    acc[2][0] = __builtin_amdgcn_mfma_f32_16x16x32_bf16(af[2], bb0, acc[2][0], 0, 0, 0);
    acc[3][0] = __builtin_amdgcn_mfma_f32_16x16x32_bf16(af[3], bb0, acc[3][0], 0, 0, 0);
    acc[0][1] = __builtin_amdgcn_mfma_f32_16x16x32_bf16(af[0], bb1, acc[0][1], 0, 0, 0);
    acc[1][1] = __builtin_amdgcn_mfma_f32_16x16x32_bf16(af[1], bb1, acc[1][1], 0, 0, 0);
    acc[2][1] = __builtin_amdgcn_mfma_f32_16x16x32_bf16(af[2], bb1, acc[2][1], 0, 0, 0);
    acc[3][1] = __builtin_amdgcn_mfma_f32_16x16x32_bf16(af[3], bb1, acc[3][1], 0, 0, 0);
  }
  __syncthreads();   // Xs dead only when ALL waves finished layer-1 LDS reads

  // bias + relu -> Y1 [64][256] bf16 (overlays Xs, 512B rows, same swizzle)
#pragma unroll
  for (int ct = 0; ct < 2; ++ct) {
    int nn = cw + ct * 16 + r;
    float bias = b1[nn];
#pragma unroll
    for (int mt = 0; mt < 4; ++mt) {
#pragma unroll
      for (int reg = 0; reg < 4; ++reg) {
        int m = mt * 16 + q * 4 + reg;
        int off = (m << 9) + ((nn << 1) ^ ((m & 7) << 4));
        *(bf16_t*)(smem + off) = (bf16_t)fmaxf(acc[mt][ct][reg] + bias, 0.0f);
      }
    }
  }
  __syncthreads();

  // ---- Layer 2: [64 x 256] x [256 x 128] -> out, wave owns 16 cols
  floatx4_t acc2[4] = {};
  const bf16_t* vq = W2T + (size_t)(wave * 16 + r) * N1;
  for (int kk = 0; kk < 8; ++kk) {
    int k0 = kk * 32 + q * 8;
    int co = (k0 << 1) ^ rs8;
    bf16x8_t a0 = *(const bf16x8_t*)(smem + ((     r) << 9) + co);
    bf16x8_t a1 = *(const bf16x8_t*)(smem + ((16 + r) << 9) + co);
    bf16x8_t a2 = *(const bf16x8_t*)(smem + ((32 + r) << 9) + co);
    bf16x8_t a3 = *(const bf16x8_t*)(smem + ((48 + r) << 9) + co);
    bf16x8_t bb = *(const bf16x8_t*)(vq + k0);
    acc2[0] = __builtin_amdgcn_mfma_f32_16x16x32_bf16(a0, bb, acc2[0], 0, 0, 0);
    acc2[1] = __builtin_amdgcn_mfma_f32_16x16x32_bf16(a1, bb, acc2[1], 0, 0, 0);
    acc2[2] = __builtin_amdgcn_mfma_f32_16x16x32_bf16(a2, bb, acc2[2], 0, 0, 0);
    acc2[3] = __builtin_amdgcn_mfma_f32_16x16x32_bf16(a3, bb, acc2[3], 0, 0, 0);
  }
  {
    int cc = wave * 16 + r;
    float bias = b2[cc];
#pragma unroll
    for (int mt = 0; mt < 4; ++mt) {
#pragma unroll
      for (int reg = 0; reg < 4; ++reg) {
        int m = mt * 16 + q * 4 + reg;
        out[(bN + m) * N2 + cc] = fmaxf(acc2[mt][reg] + bias, 0.0f);
      }
    }
  }
}

// ----------------------------------------------------------------- launch --
extern "C" void kernel_launch(void* const* d_in, const int* in_sizes, int n_in,
                              void* d_out, int out_size, void* d_ws, size_t ws_size,
                              hipStream_t stream) {
  (void)in_sizes; (void)n_in; (void)out_size; (void)ws_size;
  const float* xyz1    = (const float*)d_in[0];
  const float* xyz2    = (const float*)d_in[1];
  const float* points1 = (const float*)d_in[2];
  const float* points2 = (const float*)d_in[3];
  const float* W1      = (const float*)d_in[4];
  const float* b1      = (const float*)d_in[5];
  const float* W2      = (const float*)d_in[6];
  const float* b2      = (const float*)d_in[7];
  float* out = (float*)d_out;
  char* ws = (char*)d_ws;
  bf16_t* W1T   = (bf16_t*)(ws + WS_W1T);
  bf16_t* W2T   = (bf16_t*)(ws + WS_W2T);
  float4* xyz2p = (float4*)(ws + WS_XYZ2P);

  prep_kernel<<<576, 256, 0, stream>>>(W1, W2, xyz2, W1T, W2T, xyz2p);
  fp_fused_kernel<<<1024, 512, 0, stream>>>(xyz1, xyz2p, points1, points2,
                                            W1T, b1, W2T, b2, out);
}

// Round 4
// 215.915 us; speedup vs baseline: 1.6055x; 1.6055x over previous
//
// PointNet++ FP: three_nn + three_interpolate + pointwise MLP(384->256->128)
// Round 12: fix r11's spill catastrophe. r11 counters: VGPR=32 (forced by
// launch_bounds(512,8)), WRITE_SIZE 40->310MB, FETCH 37->179MB = scratch
// spills; VALU 36% (vmcnt waits on spill reloads). The 32KB-LDS occupancy
// win was real (74%) -- keep it, but make the skip path VGPR-LEAN:
//  * prep converts points1 -> bf16 (ws +16.8MB, runtime ws_size guard with
//    r11's f32 path as template fallback). Skip A-fragment = ONE
//    global_load_dwordx4 in MFMA layout; no f32 staging, no cvt chain.
//  * __launch_bounds__(512,6): allocator free up to 85 -> never spills; if
//    it lands <=64 we get 4 blocks/CU (32 waves, 100% slots), else 3 = r10.
//  * #pragma unroll 1 on skip loop: stop the scheduler hoisting 4 iters of
//    loads (that was r11's pressure spike).
// Scan (s_load ping-pong, wave=chunk, lane=point), fold, gather, swizzled
// Xs[64][256]/Y1 overlay, L2 all unchanged from r11.
// MFMA 16x16x32 bf16 layouts (learn_hip m89/m120 verified):
//   A: [m=lane&15][k=(lane>>4)*8+j]   B: [k=(lane>>4)*8+j][n=lane&15]
//   D: [row=(lane>>4)*4+reg][col=lane&15]
#include <hip/hip_runtime.h>

typedef __bf16 bf16_t;
typedef bf16_t bf16x2_t __attribute__((ext_vector_type(2)));
typedef bf16_t bf16x4_t __attribute__((ext_vector_type(4)));
typedef bf16_t bf16x8_t __attribute__((ext_vector_type(8)));
typedef float floatx4_t __attribute__((ext_vector_type(4)));

constexpr int B_ = 8, N_ = 8192, M_ = 2048;
constexpr int C1 = 128, C2 = 256;
constexpr int K1 = 384, N1 = 256, N2 = 128;

// ws layout (bytes)
constexpr size_t WS_W1T   = 0;         // bf16  [256][384]  = 196608 B
constexpr size_t WS_W2T   = 196608;    // bf16  [128][256]  =  65536 B
constexpr size_t WS_XYZ2P = 262144;    // float4[8*2048]    = 262144 B
constexpr size_t WS_P1B   = 524288;    // bf16  [8][8192][128] = 16777216 B
constexpr size_t WS_NEED  = WS_P1B + (size_t)B_ * N_ * C1 * 2;

// ---------------------------------------------------------------- prep ----
__global__ __launch_bounds__(256) void prep_kernel(
    const float* __restrict__ W1, const float* __restrict__ W2,
    const float* __restrict__ xyz2, const float* __restrict__ points1,
    bf16_t* __restrict__ W1T, bf16_t* __restrict__ W2T,
    float4* __restrict__ xyz2p, bf16_t* __restrict__ p1b) {
  int bid = blockIdx.x, tid = threadIdx.x;
  if (bid < 384) {                       // W1 [384][256] -> W1T [256][384]
    int t = bid * 256 + tid;             // 98304 elems
    int n = t / K1, k = t - n * K1;
    W1T[t] = (bf16_t)W1[k * N1 + n];
  } else if (bid < 512) {                // W2 [256][128] -> W2T [128][256]
    int t = (bid - 384) * 256 + tid;     // 32768 elems
    int n = t / N1, k = t - n * N1;
    W2T[t] = (bf16_t)W2[k * N2 + n];
  } else if (bid < 576) {                // xyz2 -> float4{x,y,z,|q|^2}
    int t = (bid - 512) * 256 + tid;     // 16384 elems
    const float* p = xyz2 + (size_t)t * 3;
    float x = p[0], y = p[1], z = p[2];
    xyz2p[t] = make_float4(x, y, z, x * x + y * y + z * z);
  } else {                               // points1 f32 -> bf16, 8 elems/thr
    size_t t = (size_t)(bid - 576) * 256 + tid;   // 0..1048575
    const float4* src = (const float4*)points1 + t * 2;
    float4 f0 = src[0], f1 = src[1];
    bf16x8_t v;
    v[0] = (bf16_t)f0.x; v[1] = (bf16_t)f0.y;
    v[2] = (bf16_t)f0.z; v[3] = (bf16_t)f0.w;
    v[4] = (bf16_t)f1.x; v[5] = (bf16_t)f1.y;
    v[6] = (bf16_t)f1.z; v[7] = (bf16_t)f1.w;
    *(bf16x8_t*)(p1b + t * 8) = v;
  }
}

// ---------------------------------------------- fused nn+interp+MLP -------
// 1024 blocks x 512 threads; block owns 64 points of batch b = bi&7 (XCD-local
// points2/xyz2p in that XCD's L2). Wave w = candidate chunk of 256.
template <bool USE_P1B>
__global__ __launch_bounds__(512, 6) void fp_fused_kernel(
    const float* __restrict__ xyz1, const float4* __restrict__ xyz2p,
    const float* __restrict__ points1, const bf16_t* __restrict__ p1b,
    const float* __restrict__ points2,
    const bf16_t* __restrict__ W1T, const float* __restrict__ b1,
    const bf16_t* __restrict__ W2T, const float* __restrict__ b2,
    float* __restrict__ out) {
  // Xs [64][256] bf16 swizzled (32KB); sd/si [8][64] float4/int4 overlay the
  // first 16KB during the scan; Y1 [64][256] bf16 overlays after layer 1.
  __shared__ __align__(16) char smem[64 * 512];   // 32768 B

  int bi = blockIdx.x;
  int b = bi & 7;                  // batch -> XCD (round-robin)
  int base = (bi >> 3) * 64;       // tile within batch (0..127)
  int tid = threadIdx.x;
  int wave = __builtin_amdgcn_readfirstlane(tid >> 6);  // 0..7
  int lane = tid & 63;
  size_t bN = (size_t)b * N_ + base;

  float4* sdv = (float4*)smem;             // [8][64] biased top-3 dists
  int4*   siv = (int4*)(smem + 8192);      // [8][64] top-3 indices

  float w0, w1, w2;                // blend weights (lane = point)
  int   i0, i1, i2;                // top-3 indices (lane = point)

  // ===== Phase S: three_nn. wave=chunk of 256 cands, lane=point (uniform
  // candidate addresses -> s_load ping-pong; SGPR-fed VALU). ================
  {
    const float* p1 = xyz1 + (bN + lane) * 3;
    float x = p1[0], y = p1[1], z = p1[2];
    float sq1 = x * x + y * y + z * z;
    float m2x = -2.0f * x, m2y = -2.0f * y, m2z = -2.0f * z;

    const float4* p2 = xyz2p + b * M_ + (wave << 8);  // wave-uniform base
    int jb = wave << 8;

    float cd0[4], cd1[4], cd2[4];
    int   ci0[4], ci1[4], ci2[4];
#pragma unroll
    for (int t = 0; t < 4; ++t) {
      cd0[t] = 1e30f; cd1[t] = 1e30f; cd2[t] = 1e30f;
      ci0[t] = 0; ci1[t] = 0; ci2[t] = 0;
    }
    // top-3 insert on d_rel = d2 - sq1 (per-point constant shift, same argmin)
    auto proc = [&](const float4& qv, int jj) {
      int tc = jj & 3;                       // chain id (const after unroll)
      float d = fmaf(m2x, qv.x, fmaf(m2y, qv.y, fmaf(m2z, qv.z, qv.w)));
      bool l0 = d < cd0[tc], l1 = d < cd1[tc], l2 = d < cd2[tc];
      float n0v = fminf(cd0[tc], d);
      float n1v = __builtin_amdgcn_fmed3f(d, cd0[tc], cd1[tc]);
      float n2v = __builtin_amdgcn_fmed3f(d, cd1[tc], cd2[tc]);
      int t1 = l0 ? ci0[tc] : jj;            // carry into slot1
      int t2 = l1 ? ci1[tc] : jj;            // carry into slot2
      ci0[tc] = l0 ? jj : ci0[tc];
      ci1[tc] = l1 ? t1 : ci1[tc];
      ci2[tc] = l2 ? t2 : ci2[tc];
      cd0[tc] = n0v; cd1[tc] = n1v; cd2[tc] = n2v;
    };

    float4 bA[8], bB[8];
#pragma unroll
    for (int t = 0; t < 8; ++t) bA[t] = p2[t];
    for (int j = 0; j < 256; j += 16) {
#pragma unroll
      for (int t = 0; t < 8; ++t) bB[t] = p2[j + 8 + t];
#pragma unroll
      for (int t = 0; t < 8; ++t) proc(bA[t], jb + j + t);
      if (j + 16 < 256) {
#pragma unroll
        for (int t = 0; t < 8; ++t) bA[t] = p2[j + 16 + t];
      }
#pragma unroll
      for (int t = 0; t < 8; ++t) proc(bB[t], jb + j + 8 + t);
    }

    // merge the 4 chains -> sorted s0<=s1<=s2
    float s0 = cd0[0], s1 = cd1[0], s2 = cd2[0];
    int   a0 = ci0[0], a1 = ci1[0], a2 = ci2[0];
    auto ins = [&](float d, int j) {
      if (d < s2) {
        if (d < s1) {
          s2 = s1; a2 = a1;
          if (d < s0) { s1 = s0; a1 = a0; s0 = d; a0 = j; }
          else        { s1 = d;  a1 = j; }
        } else { s2 = d; a2 = j; }
      }
    };
#pragma unroll
    for (int t = 1; t < 4; ++t) {
      ins(cd0[t], ci0[t]); ins(cd1[t], ci1[t]); ins(cd2[t], ci2[t]);
    }
    sdv[wave * 64 + lane] = make_float4(s0 + sq1, s1 + sq1, s2 + sq1, 0.0f);
    siv[wave * 64 + lane] = make_int4(a0, a1, a2, 0);
  }
  __syncthreads();

  // ===== Fold: every lane folds its point's 8 chunk-partials (redundant
  // across waves -> no serialization, results live in regs of lane=point). ===
  {
    float4 d0 = sdv[lane];  int4 x0 = siv[lane];
    float t0 = d0.x, t1 = d0.y, t2 = d0.z;
    int   a0 = x0.x, a1 = x0.y, a2 = x0.z;
    auto ins = [&](float d, int j) {
      if (d < t2) {
        if (d < t1) {
          t2 = t1; a2 = a1;
          if (d < t0) { t1 = t0; a1 = a0; t0 = d; a0 = j; }
          else        { t1 = d;  a1 = j; }
        } else { t2 = d; a2 = j; }
      }
    };
#pragma unroll
    for (int c = 1; c < 8; ++c) {
      float4 dd = sdv[c * 64 + lane];  int4 xx = siv[c * 64 + lane];
      ins(dd.x, xx.x); ins(dd.y, xx.y); ins(dd.z, xx.z);
    }
    float e0 = fmaxf(t0, 1e-10f), e1 = fmaxf(t1, 1e-10f), e2 = fmaxf(t2, 1e-10f);
    float r0 = 1.0f / e0, r1 = 1.0f / e1, r2 = 1.0f / e2;
    float rs = 1.0f / (r0 + r1 + r2);
    w0 = r0 * rs; w1 = r1 * rs; w2 = r2 * rs;
    i0 = a0; i1 = a1; i2 = a2;
  }
  __syncthreads();   // sd/si region about to be overwritten by Xs

  // ===== Phase A: gather -> Xs[64][256] bf16 swizzled =====================
  // wave w fills rows w*8..w*8+7 (interp features only).
#pragma unroll 2
  for (int i = 0; i < 8; ++i) {
    int p = wave * 8 + i;
    int j0 = __shfl(i0, p), j1 = __shfl(i1, p), j2 = __shfl(i2, p);
    float u0 = __shfl(w0, p), u1 = __shfl(w1, p), u2 = __shfl(w2, p);
    const float* g0 = points2 + ((size_t)b * M_ + j0) * C2 + lane * 4;
    const float* g1 = points2 + ((size_t)b * M_ + j1) * C2 + lane * 4;
    const float* g2 = points2 + ((size_t)b * M_ + j2) * C2 + lane * 4;
    float4 a0 = *(const float4*)g0;
    float4 a1 = *(const float4*)g1;
    float4 a2 = *(const float4*)g2;
    bf16x4_t v;
    v[0] = (bf16_t)(u0 * a0.x + u1 * a1.x + u2 * a2.x);
    v[1] = (bf16_t)(u0 * a0.y + u1 * a1.y + u2 * a2.y);
    v[2] = (bf16_t)(u0 * a0.z + u1 * a1.z + u2 * a2.z);
    v[3] = (bf16_t)(u0 * a0.w + u1 * a1.w + u2 * a2.w);
    int off = (p << 9) + ((lane * 8) ^ (i << 4));     // (p&7)==i
    *(bf16x4_t*)(smem + off) = v;
  }
  __syncthreads();

  int q = lane >> 4, r = lane & 15;
  int rs8 = (r & 7) << 4;            // row-swizzle XOR (rows r,16+r,32+r,48+r)

  // ---- Layer 1: [64 x 384] x [384 x 256] -> Y1, wave owns 32 cols
  floatx4_t acc[4][2] = {};
  int cw = wave * 32;
  const bf16_t* wq0 = W1T + (size_t)(cw +      r) * K1;
  const bf16_t* wq1 = W1T + (size_t)(cw + 16 + r) * K1;
  // interp part: K = 0..255 from LDS
  for (int kk = 0; kk < 8; ++kk) {
    int k0 = kk * 32 + q * 8;
    int co = (k0 << 1) ^ rs8;
    bf16x8_t a0 = *(const bf16x8_t*)(smem + ((     r) << 9) + co);
    bf16x8_t a1 = *(const bf16x8_t*)(smem + ((16 + r) << 9) + co);
    bf16x8_t a2 = *(const bf16x8_t*)(smem + ((32 + r) << 9) + co);
    bf16x8_t a3 = *(const bf16x8_t*)(smem + ((48 + r) << 9) + co);
    bf16x8_t bb0 = *(const bf16x8_t*)(wq0 + k0);
    bf16x8_t bb1 = *(const bf16x8_t*)(wq1 + k0);
    acc[0][0] = __builtin_amdgcn_mfma_f32_16x16x32_bf16(a0, bb0, acc[0][0], 0, 0, 0);
    acc[1][0] = __builtin_amdgcn_mfma_f32_16x16x32_bf16(a1, bb0, acc[1][0], 0, 0, 0);
    acc[2][0] = __builtin_amdgcn_mfma_f32_16x16x32_bf16(a2, bb0, acc[2][0], 0, 0, 0);
    acc[3][0] = __builtin_amdgcn_mfma_f32_16x16x32_bf16(a3, bb0, acc[3][0], 0, 0, 0);
    acc[0][1] = __builtin_amdgcn_mfma_f32_16x16x32_bf16(a0, bb1, acc[0][1], 0, 0, 0);
    acc[1][1] = __builtin_amdgcn_mfma_f32_16x16x32_bf16(a1, bb1, acc[1][1], 0, 0, 0);
    acc[2][1] = __builtin_amdgcn_mfma_f32_16x16x32_bf16(a2, bb1, acc[2][1], 0, 0, 0);
    acc[3][1] = __builtin_amdgcn_mfma_f32_16x16x32_bf16(a3, bb1, acc[3][1], 0, 0, 0);
  }
  // skip part: K = 256..383, A-fragments straight from points1 (no LDS).
  // unroll 1: do NOT let the scheduler hoist 4 iterations of loads (r11).
#pragma unroll 1
  for (int kk2 = 0; kk2 < 4; ++kk2) {
    int c0 = kk2 * 32 + q * 8;
    int k0 = 256 + c0;
    bf16x8_t af0, af1, af2, af3;
    if constexpr (USE_P1B) {
      const bf16_t* sp = p1b + (bN + r) * (size_t)C1 + c0;
      af0 = *(const bf16x8_t*)(sp);
      af1 = *(const bf16x8_t*)(sp + 16 * C1);
      af2 = *(const bf16x8_t*)(sp + 32 * C1);
      af3 = *(const bf16x8_t*)(sp + 48 * C1);
    } else {
      bf16x8_t af[4];
#pragma unroll
      for (int t = 0; t < 4; ++t) {
        const float* sp = points1 + (bN + t * 16 + r) * (size_t)C1 + c0;
        float4 f0 = *(const float4*)sp;
        float4 f1 = *(const float4*)(sp + 4);
        af[t][0] = (bf16_t)f0.x; af[t][1] = (bf16_t)f0.y;
        af[t][2] = (bf16_t)f0.z; af[t][3] = (bf16_t)f0.w;
        af[t][4] = (bf16_t)f1.x; af[t][5] = (bf16_t)f1.y;
        af[t][6] = (bf16_t)f1.z; af[t][7] = (bf16_t)f1.w;
      }
      af0 = af[0]; af1 = af[1]; af2 = af[2]; af3 = af[3];
    }
    bf16x8_t bb0 = *(const bf16x8_t*)(wq0 + k0);
    bf16x8_t bb1 = *(const bf16x8_t*)(wq1 + k0);
    acc[0][0] = __builtin_amdgcn_mfma_f32_16x16x32_bf16(af0, bb0, acc[0][0], 0, 0, 0);
    acc[1][0] = __builtin_amdgcn_mfma_f32_16x16x32_bf16(af1, bb0, acc[1][0], 0, 0, 0);
    acc[2][0] = __builtin_amdgcn_mfma_f32_16x16x32_bf16(af2, bb0, acc[2][0], 0, 0, 0);
    acc[3][0] = __builtin_amdgcn_mfma_f32_16x16x32_bf16(af3, bb0, acc[3][0], 0, 0, 0);
    acc[0][1] = __builtin_amdgcn_mfma_f32_16x16x32_bf16(af0, bb1, acc[0][1], 0, 0, 0);
    acc[1][1] = __builtin_amdgcn_mfma_f32_16x16x32_bf16(af1, bb1, acc[1][1], 0, 0, 0);
    acc[2][1] = __builtin_amdgcn_mfma_f32_16x16x32_bf16(af2, bb1, acc[2][1], 0, 0, 0);
    acc[3][1] = __builtin_amdgcn_mfma_f32_16x16x32_bf16(af3, bb1, acc[3][1], 0, 0, 0);
  }
  __syncthreads();   // Xs dead only when ALL waves finished layer-1 LDS reads

  // bias + relu -> Y1 [64][256] bf16 (overlays Xs, 512B rows, same swizzle)
#pragma unroll
  for (int ct = 0; ct < 2; ++ct) {
    int nn = cw + ct * 16 + r;
    float bias = b1[nn];
#pragma unroll
    for (int mt = 0; mt < 4; ++mt) {
#pragma unroll
      for (int reg = 0; reg < 4; ++reg) {
        int m = mt * 16 + q * 4 + reg;
        int off = (m << 9) + ((nn << 1) ^ ((m & 7) << 4));
        *(bf16_t*)(smem + off) = (bf16_t)fmaxf(acc[mt][ct][reg] + bias, 0.0f);
      }
    }
  }
  __syncthreads();

  // ---- Layer 2: [64 x 256] x [256 x 128] -> out, wave owns 16 cols
  floatx4_t acc2[4] = {};
  const bf16_t* vq = W2T + (size_t)(wave * 16 + r) * N1;
  for (int kk = 0; kk < 8; ++kk) {
    int k0 = kk * 32 + q * 8;
    int co = (k0 << 1) ^ rs8;
    bf16x8_t a0 = *(const bf16x8_t*)(smem + ((     r) << 9) + co);
    bf16x8_t a1 = *(const bf16x8_t*)(smem + ((16 + r) << 9) + co);
    bf16x8_t a2 = *(const bf16x8_t*)(smem + ((32 + r) << 9) + co);
    bf16x8_t a3 = *(const bf16x8_t*)(smem + ((48 + r) << 9) + co);
    bf16x8_t bb = *(const bf16x8_t*)(vq + k0);
    acc2[0] = __builtin_amdgcn_mfma_f32_16x16x32_bf16(a0, bb, acc2[0], 0, 0, 0);
    acc2[1] = __builtin_amdgcn_mfma_f32_16x16x32_bf16(a1, bb, acc2[1], 0, 0, 0);
    acc2[2] = __builtin_amdgcn_mfma_f32_16x16x32_bf16(a2, bb, acc2[2], 0, 0, 0);
    acc2[3] = __builtin_amdgcn_mfma_f32_16x16x32_bf16(a3, bb, acc2[3], 0, 0, 0);
  }
  {
    int cc = wave * 16 + r;
    float bias = b2[cc];
#pragma unroll
    for (int mt = 0; mt < 4; ++mt) {
#pragma unroll
      for (int reg = 0; reg < 4; ++reg) {
        int m = mt * 16 + q * 4 + reg;
        out[(bN + m) * N2 + cc] = fmaxf(acc2[mt][reg] + bias, 0.0f);
      }
    }
  }
}

// ----------------------------------------------------------------- launch --
extern "C" void kernel_launch(void* const* d_in, const int* in_sizes, int n_in,
                              void* d_out, int out_size, void* d_ws, size_t ws_size,
                              hipStream_t stream) {
  (void)in_sizes; (void)n_in; (void)out_size;
  const float* xyz1    = (const float*)d_in[0];
  const float* xyz2    = (const float*)d_in[1];
  const float* points1 = (const float*)d_in[2];
  const float* points2 = (const float*)d_in[3];
  const float* W1      = (const float*)d_in[4];
  const float* b1      = (const float*)d_in[5];
  const float* W2      = (const float*)d_in[6];
  const float* b2      = (const float*)d_in[7];
  float* out = (float*)d_out;
  char* ws = (char*)d_ws;
  bf16_t* W1T   = (bf16_t*)(ws + WS_W1T);
  bf16_t* W2T   = (bf16_t*)(ws + WS_W2T);
  float4* xyz2p = (float4*)(ws + WS_XYZ2P);
  bf16_t* p1b   = (bf16_t*)(ws + WS_P1B);

  bool use_p1b = (ws_size >= WS_NEED);
  if (use_p1b) {
    prep_kernel<<<4672, 256, 0, stream>>>(W1, W2, xyz2, points1,
                                          W1T, W2T, xyz2p, p1b);
    fp_fused_kernel<true><<<1024, 512, 0, stream>>>(
        xyz1, xyz2p, points1, p1b, points2, W1T, b1, W2T, b2, out);
  } else {
    prep_kernel<<<576, 256, 0, stream>>>(W1, W2, xyz2, points1,
                                         W1T, W2T, xyz2p, p1b);
    fp_fused_kernel<false><<<1024, 512, 0, stream>>>(
        xyz1, xyz2p, points1, p1b, points2, W1T, b1, W2T, b2, out);
  }
}